// Round 4
// baseline (60.809 us; speedup 1.0000x reference)
//
#include <hip/hip_runtime.h>

// Problem constants: N=8, C=1024, D=128, K=64, R=256
#define N_ 8
#define C_ 1024
#define D_ 128
#define K_ 64
#define R_ 256

typedef float fvec4 __attribute__((ext_vector_type(4)));  // clang-native, ok for nontemporal builtin

// out[n,c,k,d] = (xhat[n,c,d] - cent[n,k,d]) / (8 * ||xhat[n,c]-cent[n,k]||)
// xhat = x/max(||x||,eps), cent[n,k] = cluster[n, cluster_idx[k]].
// Softmax cancels exactly under the per-k l2norm; final l2norm over K*D is
// exactly sqrt(K)=8 (K unit vectors concatenated).
//
// Mapping: block = one (n,c) row, 256 threads = 8 half-waves.
// Half-wave h owns k = p*8+h for p in 0..7; lane l owns d-slice [4l, 4l+4).
// Cross-lane reduction via 32-lane xor butterflies -> no LDS, no barriers.
// R2/R3: prefetch all 8 cent rows up front; fuse store into the p-loop
// (one transient diff -> lower VGPR -> 8 waves/SIMD); nontemporal stores so
// the 268 MB output stream doesn't evict the L2-resident cluster rows.
__global__ __launch_bounds__(256) void vlad_stream_kernel(
    const float* __restrict__ x,            // (N, C, D)
    const float* __restrict__ cluster,      // (N, R, D)
    const int*   __restrict__ cluster_idx,  // (K,)
    float*       __restrict__ out)          // (N, C, K*D)
{
    const int blk = blockIdx.x;      // n*C + c
    const int n   = blk >> 10;
    const int t   = threadIdx.x;
    const int l   = t & 31;          // lane within half-wave
    const int h   = t >> 5;          // half-wave id 0..7

    // ---- issue x load + all 8 cluster-row gathers up front (independent) ----
    const float* xrow = x + (size_t)blk * D_;
    fvec4 xv = *(const fvec4*)(xrow + l * 4);            // coalesced

    const float* cbase = cluster + (size_t)n * (R_ * D_);
    fvec4 cv[8];
    #pragma unroll
    for (int p = 0; p < 8; ++p) {
        const int k = p * 8 + h;
        cv[p] = *(const fvec4*)(cbase + (size_t)cluster_idx[k] * D_ + l * 4);
    }

    // ---- x-row norm (overlaps with in-flight cv loads) ----
    float nx = fmaf(xv.x, xv.x, fmaf(xv.y, xv.y, fmaf(xv.z, xv.z, xv.w * xv.w)));
    #pragma unroll
    for (int m = 1; m <= 16; m <<= 1) nx += __shfl_xor(nx, m, 32);
    const float rinv = 1.0f / fmaxf(sqrtf(nx), 1e-12f);
    xv *= rinv;

    // ---- per-k: diff, distance butterfly, scale, nontemporal store ----
    float* orow = out + (size_t)blk * (K_ * D_) + (size_t)t * 4;
    #pragma unroll
    for (int p = 0; p < 8; ++p) {
        fvec4 d = xv - cv[p];
        float ds = fmaf(d.x, d.x, fmaf(d.y, d.y, fmaf(d.z, d.z, d.w * d.w)));
        #pragma unroll
        for (int m = 1; m <= 16; m <<= 1) ds += __shfl_xor(ds, m, 32);
        const float id = 0.125f / fmaxf(sqrtf(ds), 1e-12f);   // includes 1/sqrt(K)
        fvec4 o = d * id;
        __builtin_nontemporal_store(o, (fvec4*)(orow + (size_t)p * 1024));
    }
}

extern "C" void kernel_launch(void* const* d_in, const int* in_sizes, int n_in,
                              void* d_out, int out_size, void* d_ws, size_t ws_size,
                              hipStream_t stream) {
    const float* x           = (const float*)d_in[0];
    const float* cluster     = (const float*)d_in[1];
    // d_in[2] = conv_w, d_in[3] = conv_b: mathematically cancelled, unused.
    const int*   cluster_idx = (const int*)d_in[4];
    float* out = (float*)d_out;

    dim3 grid(N_ * C_), block(256);
    vlad_stream_kernel<<<grid, block, 0, stream>>>(x, cluster, cluster_idx, out);
}

// Round 5
// 58.338 us; speedup vs baseline: 1.0424x; 1.0424x over previous
//
#include <hip/hip_runtime.h>

// Problem constants: N=8, C=1024, D=128, K=64, R=256
#define N_ 8
#define C_ 1024
#define D_ 128
#define K_ 64
#define R_ 256

typedef float fvec4 __attribute__((ext_vector_type(4)));

// out[n,c,k,d] = (xhat[n,c,d] - cent[n,k,d]) / (8 * ||xhat[n,c]-cent[n,k]||)
// xhat = x/max(||x||,eps), cent[n,k] = cluster[n, cluster_idx[k]].
// Softmax cancels exactly under the per-k l2norm; final l2norm over K*D is
// exactly sqrt(K)=8 (K unit vectors concatenated).
//
// Mapping: block = one (n,c) row, 256 threads = 8 half-waves.
// Half-wave h owns k = p*8+h for p in 0..7; lane l owns d-slice [4l, 4l+4).
// Cross-lane reduction via 32-lane xor butterflies -> no LDS, no barriers.
//
// R4: XCD pinning. Blocks round-robin XCDs (hw_idx % 8), so decode
// n = blockIdx.x & 7 -> each XCD reads only ONE n's cluster slab (1 MB),
// fully L2-resident, instead of all 8 n's (8 MB > 4 MB L2/XCD) thrashing
// to L3 and contending with the 268 MB HBM write stream.
// Plain stores restored (nontemporal regressed 57->61 us in R3).
__global__ __launch_bounds__(256) void vlad_stream_kernel(
    const float* __restrict__ x,            // (N, C, D)
    const float* __restrict__ cluster,      // (N, R, D)
    const int*   __restrict__ cluster_idx,  // (K,)
    float*       __restrict__ out)          // (N, C, K*D)
{
    const int n   = blockIdx.x & 7;      // XCD-pinned batch index
    const int c   = blockIdx.x >> 3;
    const int blk = (n << 10) + c;       // n*C + c
    const int t   = threadIdx.x;
    const int l   = t & 31;              // lane within half-wave
    const int h   = t >> 5;              // half-wave id 0..7

    // ---- issue x load + all 8 cluster-row gathers up front (independent) ----
    const float* xrow = x + (size_t)blk * D_;
    fvec4 xv = *(const fvec4*)(xrow + l * 4);            // coalesced

    const float* cbase = cluster + (size_t)n * (R_ * D_);
    fvec4 cv[8];
    #pragma unroll
    for (int p = 0; p < 8; ++p) {
        const int k = p * 8 + h;
        cv[p] = *(const fvec4*)(cbase + (size_t)cluster_idx[k] * D_ + l * 4);
    }

    // ---- x-row norm (overlaps with in-flight cv loads) ----
    float nx = fmaf(xv.x, xv.x, fmaf(xv.y, xv.y, fmaf(xv.z, xv.z, xv.w * xv.w)));
    #pragma unroll
    for (int m = 1; m <= 16; m <<= 1) nx += __shfl_xor(nx, m, 32);
    const float rinv = 1.0f / fmaxf(sqrtf(nx), 1e-12f);
    xv *= rinv;

    // ---- per-k: diff, distance butterfly, scale, store ----
    float* orow = out + (size_t)blk * (K_ * D_) + (size_t)t * 4;
    #pragma unroll
    for (int p = 0; p < 8; ++p) {
        fvec4 d = xv - cv[p];
        float ds = fmaf(d.x, d.x, fmaf(d.y, d.y, fmaf(d.z, d.z, d.w * d.w)));
        #pragma unroll
        for (int m = 1; m <= 16; m <<= 1) ds += __shfl_xor(ds, m, 32);
        const float id = 0.125f / fmaxf(sqrtf(ds), 1e-12f);   // includes 1/sqrt(K)
        *(fvec4*)(orow + (size_t)p * 1024) = d * id;
    }
}

extern "C" void kernel_launch(void* const* d_in, const int* in_sizes, int n_in,
                              void* d_out, int out_size, void* d_ws, size_t ws_size,
                              hipStream_t stream) {
    const float* x           = (const float*)d_in[0];
    const float* cluster     = (const float*)d_in[1];
    // d_in[2] = conv_w, d_in[3] = conv_b: mathematically cancelled, unused.
    const int*   cluster_idx = (const int*)d_in[4];
    float* out = (float*)d_out;

    dim3 grid(N_ * C_), block(256);
    vlad_stream_kernel<<<grid, block, 0, stream>>>(x, cluster, cluster_idx, out);
}